// Round 1
// baseline (114.010 us; speedup 1.0000x reference)
//
#include <hip/hip_runtime.h>

#define GH 52
#define GW 52
#define NB 5
#define NBOX (GH*GW*NB)      // 13520
#define SCALE 8.0f           // 416/52
#define NORMY 416.0f
#define IOU_T 0.4f
#define LCAP 48              // list capacity per box: 1 count + up to 44 entries

// ---------------- Kernel A: decode boxes, write out[...,0:4], stash boxes+scores ----
__global__ void decode_kernel(const float* __restrict__ x, float* __restrict__ out,
                              float4* __restrict__ boxes, float* __restrict__ scores) {
    int j = blockIdx.x * blockDim.x + threadIdx.x;
    if (j >= NBOX) return;
    int cell = j / NB, b = j % NB;
    int gx = cell % GW, gy = cell / GW;
    const float* p = x + (size_t)cell * (NB * 5) + b * 5;
    float c0 = p[0], c1 = p[1], c2 = p[2], c3 = p[3], s = p[4];
    float cx = (c0 + (float)gx) * SCALE;
    float w  = c2 * SCALE;
    float cy = (c1 + (float)gy) * SCALE;
    float h  = c3 * SCALE;
    cy = NORMY - cy;
    float x1 = cx - w * 0.5f, y1 = cy - h * 0.5f;
    float x2 = cx + w * 0.5f, y2 = cy + h * 0.5f;
    out[j*5+0] = x1; out[j*5+1] = y1; out[j*5+2] = x2; out[j*5+3] = y2;
    boxes[j]  = make_float4(x1, y1, x2, y2);
    scores[j] = s;
}

// ---------------- Kernel B: build suppression predecessor lists (local: 3x3 cells) --
__global__ void adj_kernel(const float4* __restrict__ boxes, const float* __restrict__ scores,
                           unsigned short* __restrict__ nbr) {
    int j = blockIdx.x * blockDim.x + threadIdx.x;
    if (j >= NBOX) return;
    int cell = j / NB;
    int gx = cell % GW, gy = cell / GW;
    float4 bj = boxes[j];
    float sj = scores[j];
    float areaj = fmaxf(bj.z - bj.x, 0.f) * fmaxf(bj.w - bj.y, 0.f);
    int cnt = 0;
    unsigned short* lp = nbr + (size_t)j * LCAP;
    for (int dy = -1; dy <= 1; ++dy) {
        int ny = gy + dy; if (ny < 0 || ny >= GH) continue;
        for (int dx = -1; dx <= 1; ++dx) {
            int nx = gx + dx; if (nx < 0 || nx >= GW) continue;
            int base = (ny * GW + nx) * NB;
            #pragma unroll
            for (int nb = 0; nb < NB; ++nb) {
                int i = base + nb;
                if (i == j) continue;
                float si = scores[i];
                // pri(i) > pri(j): score desc, index asc (stable-argsort tiebreak)
                bool earlier = (si > sj) || (si == sj && i < j);
                if (!earlier) continue;
                float4 bi = boxes[i];
                float iw = fmaxf(fminf(bi.z, bj.z) - fmaxf(bi.x, bj.x), 0.f);
                float ih = fmaxf(fminf(bi.w, bj.w) - fmaxf(bi.y, bj.y), 0.f);
                float inter = iw * ih;
                float areai = fmaxf(bi.z - bi.x, 0.f) * fmaxf(bi.w - bi.y, 0.f);
                float uni = areai + areaj - inter;
                float iou = (uni > 0.f) ? inter / fmaxf(uni, 1e-12f) : 0.f;
                if (iou > IOU_T) { lp[1 + cnt] = (unsigned short)i; ++cnt; }
            }
        }
    }
    lp[0] = (unsigned short)cnt;
}

// ---------------- Kernel C: chaotic fixpoint of active[j] = NOR(active[preds]) -----
// Unique fixpoint on the suppression DAG == exact greedy NMS result.
__global__ __launch_bounds__(1024) void nms_kernel(const unsigned short* __restrict__ nbr,
                                                   const float* __restrict__ scores,
                                                   float* __restrict__ out) {
    __shared__ unsigned char active_s[NBOX];
    __shared__ int changed;
    int tid = threadIdx.x;
    for (int j = tid; j < NBOX; j += 1024) active_s[j] = 1;
    __syncthreads();
    volatile unsigned char* act = active_s;

    for (int pass = 0; pass < 256; ++pass) {
        if (tid == 0) changed = 0;
        __syncthreads();                       // A: reset visible
        bool mych = false;
        for (int j = tid; j < NBOX; j += 1024) {
            const unsigned short* lp = nbr + (size_t)j * LCAP;
            int cnt = lp[0];
            int sup = 0;
            for (int k = 1; k <= cnt; ++k) sup |= act[lp[k]];
            unsigned char na = sup ? 0 : 1;
            if (na != act[j]) { act[j] = na; mych = true; }
        }
        if (mych) changed = 1;
        __syncthreads();                       // B: all writes done
        int ch = changed;
        __syncthreads();                       // C: everyone read flag before next reset
        if (!ch) break;
    }

    for (int j = tid; j < NBOX; j += 1024)
        out[j*5+4] = act[j] ? scores[j] : 0.0f;
}

extern "C" void kernel_launch(void* const* d_in, const int* in_sizes, int n_in,
                              void* d_out, int out_size, void* d_ws, size_t ws_size,
                              hipStream_t stream) {
    const float* x = (const float*)d_in[0];
    float* out = (float*)d_out;

    // ws layout: boxes float4[NBOX] | scores float[NBOX] | nbr u16[NBOX][LCAP]
    char* ws = (char*)d_ws;
    float4* boxes  = (float4*)ws;                               // 216320 B
    float*  scores = (float*)(ws + (size_t)NBOX * 16);          //  54080 B
    unsigned short* nbr = (unsigned short*)(ws + (size_t)NBOX * 16 + (size_t)NBOX * 4);

    int blk = 256;
    int grd = (NBOX + blk - 1) / blk;
    decode_kernel<<<grd, blk, 0, stream>>>(x, out, boxes, scores);
    adj_kernel<<<grd, blk, 0, stream>>>(boxes, scores, nbr);
    nms_kernel<<<1, 1024, 0, stream>>>(nbr, scores, out);
}